// Round 3
// baseline (255.840 us; speedup 1.0000x reference)
//
#include <hip/hip_runtime.h>
#include <hip/hip_bf16.h>

#define IN_CH 512
#define OUT_CH 512
#define Z_DIM 512
#define BATCH 8
#define EPS 1e-8f
#define SLOPE 0.2f
#define GAIN 1.4142135623730951f
#define INV_SQRT512 0.04419417382415922f

#define BM 128
#define BN 512
#define BK 32
#define NSTEP (IN_CH / BK)   // 16 K-steps

typedef short bf16x8 __attribute__((ext_vector_type(8)));
typedef float f32x4 __attribute__((ext_vector_type(4)));

__device__ __forceinline__ unsigned short f2bf(float f) {
  unsigned int u = __float_as_uint(f);
  u += 0x7FFF + ((u >> 16) & 1);   // RNE
  return (unsigned short)(u >> 16);
}

// async global->LDS, 16B per lane; lds base must be wave-uniform
__device__ __forceinline__ void async16(void* lds, const void* g) {
  __builtin_amdgcn_global_load_lds(
      (const __attribute__((address_space(1))) unsigned int*)(unsigned long long)g,
      (__attribute__((address_space(3))) unsigned int*)(unsigned int)(unsigned long long)lds,
      16, 0, 0);
}

// byte offset in a [rows][32] bf16 tile (64 B row stride), XOR slot swizzle:
// phys_slot = logical_slot ^ ((row>>1)&3)  -> 2-way (free) bank access on
// ds_read_b128 fragment reads (16 rows, same slot).
__device__ __forceinline__ int tile_off(int row, int slot) {
  return row * 64 + (((slot ^ (row >> 1)) & 3) << 4);
}

// ---------------- prep: gamma[b][c] and demodulated bf16 weight ----------------
// blocks 0..127: wave per c, all 8 batches.  blocks 128..255: wave per o.
__global__ __launch_bounds__(256) void prep_kernel(
    const float* __restrict__ z, const float* __restrict__ weight,
    const float* __restrict__ mod_weight, const float* __restrict__ mod_bias,
    float* __restrict__ gamma_out, unsigned short* __restrict__ wd_out) {
  const int wv = threadIdx.x >> 6, lane = threadIdx.x & 63;
  if (blockIdx.x < 128) {
    const int c = blockIdx.x * 4 + wv;
    const float4* mw = (const float4*)(mod_weight + (size_t)c * Z_DIM);
    float4 a0 = mw[lane * 2], a1 = mw[lane * 2 + 1];
    float acc[BATCH];
#pragma unroll
    for (int b = 0; b < BATCH; ++b) {
      const float4* zp = (const float4*)(z + (size_t)b * Z_DIM);
      float4 z0 = zp[lane * 2], z1 = zp[lane * 2 + 1];
      float s = a0.x * z0.x + a0.y * z0.y + a0.z * z0.z + a0.w * z0.w
              + a1.x * z1.x + a1.y * z1.y + a1.z * z1.z + a1.w * z1.w;
#pragma unroll
      for (int m = 32; m; m >>= 1) s += __shfl_xor(s, m, 64);
      acc[b] = s;
    }
    if (lane == 0) {
      float mb = mod_bias[c];
#pragma unroll
      for (int b = 0; b < BATCH; ++b)
        gamma_out[b * IN_CH + c] = acc[b] * INV_SQRT512 + mb;
    }
  } else {
    const int o = (blockIdx.x - 128) * 4 + wv;
    const float4* wp = (const float4*)(weight + (size_t)o * IN_CH);
    float4 w0 = wp[lane * 2], w1 = wp[lane * 2 + 1];
    float v[8] = {w0.x, w0.y, w0.z, w0.w, w1.x, w1.y, w1.z, w1.w};
    float ss = 0.f;
#pragma unroll
    for (int e = 0; e < 8; ++e) { v[e] *= INV_SQRT512; ss += v[e] * v[e]; }
#pragma unroll
    for (int m = 32; m; m >>= 1) ss += __shfl_xor(ss, m, 64);
    float t = rsqrtf(ss + EPS);
    bf16x8 pk;
#pragma unroll
    for (int e = 0; e < 8; ++e) pk[e] = (short)f2bf(v[e] * t);
    *(bf16x8*)(wd_out + (size_t)o * IN_CH + lane * 8) = pk;
  }
}

// ---------------- fused GEMM: out = lrelu(s_m * (xg @ wd^T) + bias) * sqrt2 ----
__global__ __launch_bounds__(512, 2) void modlin_main_kernel(
    const float* __restrict__ input, const float* __restrict__ gamma_g,
    const unsigned short* __restrict__ wd, const float* __restrict__ act_bias,
    float* __restrict__ out) {
  __shared__ __align__(16) unsigned short Atile[2][BM * BK];   // 8 KB each
  __shared__ __align__(16) unsigned short Btile[2][BN * BK];   // 32 KB each
  __shared__ __align__(16) float gamma_s[IN_CH];
  __shared__ float rowss_s[BM];

  const int tid = threadIdx.x;
  const int lane = tid & 63;
  const int wv = tid >> 6;      // 0..7
  const int wm = wv >> 2;       // M half of wave
  const int wn = wv & 3;        // N quarter of wave
  const int tm = blockIdx.x;    // M tile (0..511)
  const int m0 = tm * BM;
  const int b = tm >> 6;        // batch (64 tiles per batch, exact)

  // A staging: 4 threads per row, each owns 8 cols (one 16B slot)
  const int arow = tid >> 2;    // 0..127
  const int aq = tid & 3;       // logical slot
  // B staging via global_load_lds: per call, 16 rows x 64 B, 4 lanes/row
  const int brow_in_g = lane >> 2;
  const int bp = lane & 3;      // phys slot HW writes for this lane

  f32x4 acc[4][8];
#pragma unroll
  for (int i = 0; i < 4; ++i)
#pragma unroll
    for (int j = 0; j < 8; ++j) acc[i][j] = (f32x4){0.f, 0.f, 0.f, 0.f};

  if (tid < 128)
    ((float4*)gamma_s)[tid] = ((const float4*)(gamma_g + b * IN_CH))[tid];

  const float* arow_ptr = input + (size_t)(m0 + arow) * IN_CH + aq * 8;
  float ss = 0.f;

  auto stage_B = [&](int buf, int k0) {
#pragma unroll
    for (int q = 0; q < 4; ++q) {
      int g = wv * 4 + q;
      int o = g * 16 + brow_in_g;
      int lslot = (bp ^ (o >> 1)) & 3;  // pre-swizzled source slot
      const unsigned short* src = wd + (size_t)o * IN_CH + k0 + lslot * 8;
      async16((void*)(Btile[buf] + g * 512), src);
    }
  };

  auto process_A = [&](int buf, int k0, float4 v0, float4 v1) {
    const float* gp = gamma_s + k0 + aq * 8;
    float4 g0 = ((const float4*)gp)[0];
    float4 g1 = ((const float4*)gp)[1];
    float x0 = v0.x * g0.x, x1 = v0.y * g0.y, x2 = v0.z * g0.z, x3 = v0.w * g0.w;
    float x4 = v1.x * g1.x, x5 = v1.y * g1.y, x6 = v1.z * g1.z, x7 = v1.w * g1.w;
    ss += x0 * x0 + x1 * x1 + x2 * x2 + x3 * x3
        + x4 * x4 + x5 * x5 + x6 * x6 + x7 * x7;
    bf16x8 pk;
    pk[0] = (short)f2bf(x0); pk[1] = (short)f2bf(x1);
    pk[2] = (short)f2bf(x2); pk[3] = (short)f2bf(x3);
    pk[4] = (short)f2bf(x4); pk[5] = (short)f2bf(x5);
    pk[6] = (short)f2bf(x6); pk[7] = (short)f2bf(x7);
    *(bf16x8*)((char*)Atile[buf] + tile_off(arow, aq)) = pk;
  };

  // prologue: tile 0
  float4 av0 = ((const float4*)arow_ptr)[0];
  float4 av1 = ((const float4*)arow_ptr)[1];
  stage_B(0, 0);
  __syncthreads();              // gamma_s visible
  process_A(0, 0, av0, av1);
  __syncthreads();              // buf0 (A ds_write + B vmcnt) ready

  int cur = 0;
  for (int t = 0; t < NSTEP; ++t) {
    const int k0n = (t + 1) * BK;
    float4 nv0, nv1;
    if (t + 1 < NSTEP) {
      nv0 = ((const float4*)(arow_ptr + k0n))[0];
      nv1 = ((const float4*)(arow_ptr + k0n))[1];
      stage_B(cur ^ 1, k0n);
    }
    const char* Ab = (const char*)Atile[cur];
    const char* Bb = (const char*)Btile[cur];
    const int sl = lane >> 4;
    bf16x8 af[4], bfr[8];
#pragma unroll
    for (int i = 0; i < 4; ++i) {
      int r = wm * 64 + i * 16 + (lane & 15);
      af[i] = *(const bf16x8*)(Ab + tile_off(r, sl));
    }
#pragma unroll
    for (int j = 0; j < 8; ++j) {
      int o = wn * 128 + j * 16 + (lane & 15);
      bfr[j] = *(const bf16x8*)(Bb + tile_off(o, sl));
    }
#pragma unroll
    for (int i = 0; i < 4; ++i)
#pragma unroll
      for (int j = 0; j < 8; ++j)
        acc[i][j] = __builtin_amdgcn_mfma_f32_16x16x32_bf16(af[i], bfr[j], acc[i][j], 0, 0, 0);
    if (t + 1 < NSTEP) process_A(cur ^ 1, k0n, nv0, nv1);
    __syncthreads();
    cur ^= 1;
  }

  // per-row sumsq reduce (4 staging lanes per row are lane quads)
  ss += __shfl_xor(ss, 1, 64);
  ss += __shfl_xor(ss, 2, 64);
  if ((tid & 3) == 0) rowss_s[arow] = ss;
  __syncthreads();

  // epilogue: scale by s_m, bias, leaky-relu, store f32
  float bias_j[8];
#pragma unroll
  for (int j = 0; j < 8; ++j) bias_j[j] = act_bias[wn * 128 + j * 16 + (lane & 15)];
#pragma unroll
  for (int i = 0; i < 4; ++i) {
#pragma unroll
    for (int r = 0; r < 4; ++r) {
      int lr = wm * 64 + i * 16 + (lane >> 4) * 4 + r;
      float s = rsqrtf(rowss_s[lr] + EPS);
      float* orow = out + (size_t)(m0 + lr) * OUT_CH + wn * 128 + (lane & 15);
#pragma unroll
      for (int j = 0; j < 8; ++j) {
        float v = acc[i][j][r] * s + bias_j[j];
        v = (v > 0.f ? v : v * SLOPE) * GAIN;
        orow[j * 16] = v;
      }
    }
  }
}

extern "C" void kernel_launch(void* const* d_in, const int* in_sizes, int n_in,
                              void* d_out, int out_size, void* d_ws, size_t ws_size,
                              hipStream_t stream) {
  const float* input      = (const float*)d_in[0];
  const float* z          = (const float*)d_in[1];
  const float* weight     = (const float*)d_in[2];
  const float* mod_weight = (const float*)d_in[3];
  const float* mod_bias   = (const float*)d_in[4];
  const float* act_bias   = (const float*)d_in[5];
  float* out = (float*)d_out;

  unsigned short* wd = (unsigned short*)d_ws;                 // 512*512*2 = 512 KB
  float* gamma = (float*)((char*)d_ws + 512 * 1024);          // 16 KB

  prep_kernel<<<256, 256, 0, stream>>>(z, weight, mod_weight, mod_bias, gamma, wd);
  modlin_main_kernel<<<512, 512, 0, stream>>>(input, gamma, wd, act_bias, out);
}